// Round 4
// baseline (89.001 us; speedup 1.0000x reference)
//
#include <hip/hip_runtime.h>
#include <math.h>

typedef __attribute__((ext_vector_type(8))) _Float16 f16x8;
typedef __attribute__((ext_vector_type(2))) _Float16 f16x2;
typedef __attribute__((ext_vector_type(4))) float f32x4;

// ============================ MFMA fused kernel ============================
// out[b,j] = sum_k F(b,k) * W(k,j), k = c*64 + i  (c: 0=silu base, 1..5=basis)
// BM=64 rows/block, TPB=256 (4 waves), LDS exactly 80KB -> 2 blocks/CU so one
// block's barrier drains overlap the other block's MFMA/VALU (m114).

#define TPB 256
#define BM  64

// LDS layout (bytes)
#define F_OFF   0          // F tile: 64 rows x 384 k x f16 = 49152, XOR-swizzled
#define W_OFF   49152      // W chunk double buffer: 2 x 8192
#define H_OFF   65536      // h tile: 64 x 128 x f16 = 16384
#define LDS_TOT 81920      // 80 KB exactly -> 2 blocks/CU (160KB/CU)

__global__ __launch_bounds__(TPB, 2) void kan_mfma_kernel(
    const float* __restrict__ x, const _Float16* __restrict__ W0t,
    const _Float16* __restrict__ W1t, float* __restrict__ out)
{
    __shared__ char smem[LDS_TOT];
    const int tid  = threadIdx.x;
    const int lane = tid & 63;
    const int wid  = tid >> 6;          // 4 waves
    const int wr   = wid >> 1;          // 0..1  (32-row strip)
    const int wc   = wid & 1;           // 0..1  (64-col / 32-col strip)
    const int gq   = lane >> 4;         // k-group 0..3
    const int lm   = lane & 15;
    const long rowbase = (long)blockIdx.x * BM;

    // --- basis table -> piecewise-linear consts (computed per thread, exact) ---
    float FS0[5], FB0[5], FS1[5], FB1[5];
    {
        float bvv[3][5];
        #pragma unroll
        for (int g = 0; g < 3; ++g) {
            float gv = (float)g - 1.0f;
            float e[5]; float s = 0.f;
            #pragma unroll
            for (int i = 0; i < 5; ++i) {
                float cc = -0.8125f + 0.325f * (float)i;   // (knots[i+1]+knots[i+2])/2
                float d  = (gv - cc) * (1.0f / 0.65f);     // width 0.65
                e[i] = __expf(-d * d); s += e[i];
            }
            float inv = 1.0f / (s + 1e-6f);
            #pragma unroll
            for (int i = 0; i < 5; ++i) bvv[g][i] = e[i] * inv;
        }
        #pragma unroll
        for (int c = 0; c < 5; ++c) {
            FS0[c] = bvv[1][c] - bvv[0][c];  FB0[c] = bvv[0][c];
            FS1[c] = bvv[2][c] - bvv[1][c];  FB1[c] = 2.f * bvv[1][c] - bvv[2][c];
        }
    }

    // features: f[0]=silu(v), f[1..5]=lerped basis (piecewise-linear in gi)
    auto feats6 = [&](float v, float* f) {
        float sg = 1.0f / (1.0f + __expf(-v));
        f[0] = v * sg;
        float gi = fminf(fmaxf(v, -1.f), 1.f) + 1.f;   // [0,2]
        bool s1 = gi >= 1.0f;
        #pragma unroll
        for (int c = 0; c < 5; ++c)
            f[c + 1] = fmaf(gi, s1 ? FS1[c] : FS0[c], s1 ? FB1[c] : FB0[c]);
    };

    // F write: row r, pair i2 -> k = c*64 + 2*i2; byte ^= (r&7)<<4 (T2 swizzle)
    auto writeF = [&](int r, int i2, float va, float vb) {
        float fa[6], fb[6];
        feats6(va, fa); feats6(vb, fb);
        int swz = (r & 7) << 4;
        #pragma unroll
        for (int c = 0; c < 6; ++c) {
            int byte = (r * 768 + c * 128 + 4 * i2) ^ swz;
            *(f16x2*)(smem + F_OFF + byte) = f16x2{(_Float16)fa[c], (_Float16)fb[c]};
        }
    };

    // ---------------- build F0 from x (coalesced float2 per thread) ----------------
    #pragma unroll
    for (int p = 0; p < 8; ++p) {
        int idx = tid + p * TPB;            // 0..2047 : 64 rows x 32 pairs
        int r = idx >> 5, i2 = idx & 31;
        float2 v = *(const float2*)(x + (rowbase + r) * 64 + 2 * i2);
        writeF(r, i2, v.x, v.y);
    }

    // ---------------- pass 0: h[64 rows][128 cols], K=384 ----------------
    f32x4 acc0[2][4] = {};
    const float4* w0g = (const float4*)W0t;
    float4 wra = w0g[tid], wrb = w0g[256 + tid];          // chunk 0 (8 KB)
    *(float4*)(smem + W_OFF + tid * 16) = wra;
    *(float4*)(smem + W_OFF + tid * 16 + 4096) = wrb;
    __syncthreads();                                      // F0 + W chunk0 visible

    for (int kt = 0; kt < 12; ++kt) {
        if (kt < 11) {
            wra = w0g[(kt + 1) * 512 + tid];
            wrb = w0g[(kt + 1) * 512 + 256 + tid];
        }
        const char* wb = smem + W_OFF + (kt & 1) * 8192;
        f16x8 a[2], b[4];
        #pragma unroll
        for (int mi = 0; mi < 2; ++mi) {
            int row  = wr * 32 + mi * 16 + lm;
            int byte = (row * 768 + kt * 64 + gq * 16) ^ ((row & 7) << 4);
            a[mi] = *(const f16x8*)(smem + F_OFF + byte);
        }
        #pragma unroll
        for (int nf = 0; nf < 4; ++nf)
            b[nf] = *(const f16x8*)(wb + (gq * 128 + wc * 64 + nf * 16 + lm) * 16);
        #pragma unroll
        for (int mi = 0; mi < 2; ++mi)
            #pragma unroll
            for (int nf = 0; nf < 4; ++nf)
                acc0[mi][nf] = __builtin_amdgcn_mfma_f32_16x16x32_f16(
                    a[mi], b[nf], acc0[mi][nf], 0, 0, 0);
        if (kt < 11) {
            char* nb = smem + W_OFF + ((kt + 1) & 1) * 8192;
            *(float4*)(nb + tid * 16) = wra;
            *(float4*)(nb + tid * 16 + 4096) = wrb;
        }
        __syncthreads();
    }

    // h -> LDS f16 (C/D layout: row = gq*4+reg, col = lm; verified m89)
    #pragma unroll
    for (int mi = 0; mi < 2; ++mi)
        #pragma unroll
        for (int nf = 0; nf < 4; ++nf)
            #pragma unroll
            for (int rg = 0; rg < 4; ++rg) {
                int row = wr * 32 + mi * 16 + gq * 4 + rg;
                int col = wc * 64 + nf * 16 + lm;
                *(_Float16*)(smem + H_OFF + row * 256 + col * 2) = (_Float16)acc0[mi][nf][rg];
            }
    __syncthreads();

    // ---------------- passes 1,2: out[64][64], K=2x384 over i2 halves ----------------
    f32x4 accO[2][2] = {};
    const float4* w1g = (const float4*)W1t;
    for (int half = 0; half < 2; ++half) {
        // rebuild F from h[:, half*64 : half*64+64]
        #pragma unroll
        for (int p = 0; p < 8; ++p) {
            int idx = tid + p * TPB;
            int r = idx >> 5, i2 = idx & 31;
            f16x2 hv = *(const f16x2*)(smem + H_OFF + r * 256 + half * 128 + 4 * i2);
            writeF(r, i2, (float)hv[0], (float)hv[1]);
        }
        int cb = half * 12 * 256;                          // float4 base of this half
        float4 wreg1 = w1g[cb + tid];                      // chunk 0 (4 KB)
        *(float4*)(smem + W_OFF + tid * 16) = wreg1;
        __syncthreads();                                   // F + W chunk0 visible

        for (int kt = 0; kt < 12; ++kt) {
            if (kt < 11) wreg1 = w1g[cb + (kt + 1) * 256 + tid];
            const char* wb = smem + W_OFF + (kt & 1) * 8192;
            f16x8 a[2], b[2];
            #pragma unroll
            for (int mi = 0; mi < 2; ++mi) {
                int row  = wr * 32 + mi * 16 + lm;
                int byte = (row * 768 + kt * 64 + gq * 16) ^ ((row & 7) << 4);
                a[mi] = *(const f16x8*)(smem + F_OFF + byte);
            }
            #pragma unroll
            for (int nf = 0; nf < 2; ++nf)
                b[nf] = *(const f16x8*)(wb + (gq * 64 + wc * 32 + nf * 16 + lm) * 16);
            #pragma unroll
            for (int mi = 0; mi < 2; ++mi)
                #pragma unroll
                for (int nf = 0; nf < 2; ++nf)
                    accO[mi][nf] = __builtin_amdgcn_mfma_f32_16x16x32_f16(
                        a[mi], b[nf], accO[mi][nf], 0, 0, 0);
            if (kt < 11)
                *(float4*)(smem + W_OFF + ((kt + 1) & 1) * 8192 + tid * 16) = wreg1;
            __syncthreads();
        }
    }

    // ---------------- store out ----------------
    float* og = out + rowbase * 64;
    #pragma unroll
    for (int mi = 0; mi < 2; ++mi)
        #pragma unroll
        for (int nf = 0; nf < 2; ++nf)
            #pragma unroll
            for (int rg = 0; rg < 4; ++rg) {
                int row = wr * 32 + mi * 16 + gq * 4 + rg;
                int col = wc * 32 + nf * 16 + lm;
                og[row * 64 + col] = accO[mi][nf][rg];
            }
}

// ------------- pre-kernel: combine imp/bw/sw/cp -> tiled f16 weights -------------
// W0t flat f = ((kt*4+g)*128 + n)*8 + e ; k = kt*32+g*8+e ; c=k>>6 ; i=k&63
// W1t flat f = (((half*12+kt)*4+g)*64 + n)*8 + e ; i2 = (k&63)+half*64
__global__ __launch_bounds__(256) void kan_combine_w(
    const float* __restrict__ cp0, const float* __restrict__ bw0,
    const float* __restrict__ sw0, const float* __restrict__ imp0,
    const float* __restrict__ cp1, const float* __restrict__ bw1,
    const float* __restrict__ sw1, const float* __restrict__ imp1,
    _Float16* __restrict__ W0t, _Float16* __restrict__ W1t)
{
    int f = blockIdx.x * 256 + threadIdx.x;
    if (f < 49152) {
        int e = f & 7, n = (f >> 3) & 127, g = (f >> 10) & 3, kt = f >> 12;
        int k = kt * 32 + g * 8 + e, c = k >> 6, i = k & 63;
        int edge = i * 128 + n;
        float w = imp0[edge] * ((c == 0) ? bw0[edge] : sw0[edge] * cp0[edge * 5 + (c - 1)]);
        W0t[f] = (_Float16)w;
    } else {
        int f2 = f - 49152;
        int e = f2 & 7, n = (f2 >> 3) & 63, g = (f2 >> 9) & 3;
        int q = f2 >> 11;                 // 0..23
        int half = q / 12, kt = q - half * 12;
        int kl = kt * 32 + g * 8 + e, c = kl >> 6;
        int i2 = (kl & 63) + half * 64;
        int edge = i2 * 64 + n;
        float w = imp1[edge] * ((c == 0) ? bw1[edge] : sw1[edge] * cp1[edge * 5 + (c - 1)]);
        W1t[f2] = (_Float16)w;
    }
}

// ===================== fallback: proven fp32 kernel (round 2) =====================
#define NTHR 256
#define JT 32
#define WS8 8

#define STAGE_L0(JBASE) do {                                                  \
    _Pragma("unroll")                                                         \
    for (int p = 0; p < 8; ++p) {                                             \
        int idx = tid + p * NTHR;                                             \
        int i  = idx >> 5;                                                    \
        int jj = idx & 31;                                                    \
        int e  = i * 128 + (JBASE) + jj;                                      \
        float im = imp0[e];                                                   \
        float wb = bw0[e] * im;                                               \
        float ws = sw0[e] * im;                                               \
        const float* cp = cp0 + e * 5;                                        \
        float* wp = wbuf + idx * WS8;                                         \
        wp[0] = wb;                                                           \
        wp[1] = ws * cp[0]; wp[2] = ws * cp[1]; wp[3] = ws * cp[2];           \
        wp[4] = ws * cp[3]; wp[5] = ws * cp[4];                               \
    }                                                                         \
} while (0)

#define STAGE_L1(IBASE, JBASE) do {                                           \
    _Pragma("unroll")                                                         \
    for (int p = 0; p < 8; ++p) {                                             \
        int idx = tid + p * NTHR;                                             \
        int ii = idx >> 5;                                                    \
        int jj = idx & 31;                                                    \
        int e  = ((IBASE) + ii) * 64 + (JBASE) + jj;                          \
        float im = imp1[e];                                                   \
        float wb = bw1[e] * im;                                               \
        float ws = sw1[e] * im;                                               \
        const float* cp = cp1 + e * 5;                                        \
        float* wp = wbuf + idx * WS8;                                         \
        wp[0] = wb;                                                           \
        wp[1] = ws * cp[0]; wp[2] = ws * cp[1]; wp[3] = ws * cp[2];           \
        wp[4] = ws * cp[3]; wp[5] = ws * cp[4];                               \
    }                                                                         \
} while (0)

#define COMPUTE_TILE(ACC) do {                                                \
    _Pragma("unroll 2")                                                       \
    for (int i = 0; i < 64; ++i) {                                            \
        float v  = vbuf[i][tid];                                              \
        float sg = 1.0f / (1.0f + __expf(-v));                                \
        float base = v * sg;                                                  \
        float xc = fminf(fmaxf(v, -1.0f), 1.0f);                              \
        float gi = xc + 1.0f;                                                 \
        int lo = (int)gi; lo = (lo > 2) ? 2 : lo;                             \
        float fr = gi - (float)lo;                                            \
        int hi = (fr > 0.0f) ? (lo + 1) : lo;                                 \
        float b0 = bvt[lo][0]; b0 += (bvt[hi][0] - b0) * fr;                  \
        float b1 = bvt[lo][1]; b1 += (bvt[hi][1] - b1) * fr;                  \
        float b2 = bvt[lo][2]; b2 += (bvt[hi][2] - b2) * fr;                  \
        float b3 = bvt[lo][3]; b3 += (bvt[hi][3] - b3) * fr;                  \
        float b4 = bvt[lo][4]; b4 += (bvt[hi][4] - b4) * fr;                  \
        const float* wr = wbuf + i * (JT * WS8);                              \
        _Pragma("unroll")                                                     \
        for (int jj = 0; jj < JT; ++jj) {                                     \
            const float* wp = wr + jj * WS8;                                  \
            float a = ACC[jj];                                                \
            a = fmaf(wp[0], base, a);                                         \
            a = fmaf(wp[1], b0, a);                                           \
            a = fmaf(wp[2], b1, a);                                           \
            a = fmaf(wp[3], b2, a);                                           \
            a = fmaf(wp[4], b3, a);                                           \
            a = fmaf(wp[5], b4, a);                                           \
            ACC[jj] = a;                                                      \
        }                                                                     \
    }                                                                         \
} while (0)

__global__ __launch_bounds__(NTHR) void kan_fused_kernel(
    const float* __restrict__ x,
    const float* __restrict__ cp0, const float* __restrict__ bw0,
    const float* __restrict__ sw0, const float* __restrict__ imp0,
    const float* __restrict__ cp1, const float* __restrict__ bw1,
    const float* __restrict__ sw1, const float* __restrict__ imp1,
    float* __restrict__ out)
{
    __shared__ float vbuf[64][NTHR + 1];
    __shared__ float wbuf[64 * JT * WS8];
    __shared__ float bvt[3][8];

    const int tid = threadIdx.x;

    if (tid < 3) {
        float gv = -1.0f + (float)tid;
        float e[5];
        float s = 0.0f;
        #pragma unroll
        for (int i = 0; i < 5; ++i) {
            float c = -0.8125f + 0.325f * (float)i;
            float d = (gv - c) * (1.0f / 0.65f);
            e[i] = expf(-d * d);
            s += e[i];
        }
        float inv = 1.0f / (s + 1e-6f);
        #pragma unroll
        for (int i = 0; i < 5; ++i) bvt[tid][i] = e[i] * inv;
    }

    {
        const float4* xg = (const float4*)(x + (size_t)blockIdx.x * (NTHR * 64));
        #pragma unroll
        for (int it = 0; it < 16; ++it) {
            int e4 = tid + it * NTHR;
            float4 v = xg[e4];
            int r  = e4 >> 4;
            int ib = (e4 & 15) << 2;
            vbuf[ib + 0][r] = v.x;
            vbuf[ib + 1][r] = v.y;
            vbuf[ib + 2][r] = v.z;
            vbuf[ib + 3][r] = v.w;
        }
    }
    __syncthreads();

    float h0[32] = {}, h1[32] = {}, h2[32] = {}, h3[32] = {};
    STAGE_L0(0);   __syncthreads(); COMPUTE_TILE(h0); __syncthreads();
    STAGE_L0(32);  __syncthreads(); COMPUTE_TILE(h1); __syncthreads();
    STAGE_L0(64);  __syncthreads(); COMPUTE_TILE(h2); __syncthreads();
    STAGE_L0(96);  __syncthreads(); COMPUTE_TILE(h3); __syncthreads();

    #pragma unroll
    for (int i = 0; i < 32; ++i) vbuf[i][tid] = h0[i];
    #pragma unroll
    for (int i = 0; i < 32; ++i) vbuf[32 + i][tid] = h1[i];

    float o0[32] = {}, o1[32] = {};
    STAGE_L1(0, 0);   __syncthreads(); COMPUTE_TILE(o0); __syncthreads();
    STAGE_L1(0, 32);  __syncthreads(); COMPUTE_TILE(o1); __syncthreads();

    #pragma unroll
    for (int i = 0; i < 32; ++i) vbuf[i][tid] = h2[i];
    #pragma unroll
    for (int i = 0; i < 32; ++i) vbuf[32 + i][tid] = h3[i];

    STAGE_L1(64, 0);  __syncthreads(); COMPUTE_TILE(o0); __syncthreads();
    STAGE_L1(64, 32); __syncthreads(); COMPUTE_TILE(o1);

    float4* og = (float4*)(out + (size_t)blockIdx.x * (NTHR * 64) + (size_t)tid * 64);
    #pragma unroll
    for (int q = 0; q < 8; ++q)
        og[q] = make_float4(o0[4 * q + 0], o0[4 * q + 1], o0[4 * q + 2], o0[4 * q + 3]);
    #pragma unroll
    for (int q = 0; q < 8; ++q)
        og[8 + q] = make_float4(o1[4 * q + 0], o1[4 * q + 1], o1[4 * q + 2], o1[4 * q + 3]);
}

// =================================== launch ===================================
extern "C" void kernel_launch(void* const* d_in, const int* in_sizes, int n_in,
                              void* d_out, int out_size, void* d_ws, size_t ws_size,
                              hipStream_t stream) {
    const float* x    = (const float*)d_in[0];
    const float* cp0  = (const float*)d_in[1];
    const float* bw0  = (const float*)d_in[2];
    const float* sw0  = (const float*)d_in[3];
    const float* imp0 = (const float*)d_in[4];
    const float* cp1  = (const float*)d_in[5];
    const float* bw1  = (const float*)d_in[6];
    const float* sw1  = (const float*)d_in[7];
    const float* imp1 = (const float*)d_in[8];
    float* out = (float*)d_out;

    const int B = in_sizes[0] / 64;                 // 131072
    const size_t need = 98304 * sizeof(_Float16);   // 192 KB combined weights

    if (ws_size >= need && (B % BM) == 0) {
        _Float16* W0t = (_Float16*)d_ws;
        _Float16* W1t = W0t + 49152;
        kan_combine_w<<<384, 256, 0, stream>>>(cp0, bw0, sw0, imp0,
                                               cp1, bw1, sw1, imp1, W0t, W1t);
        kan_mfma_kernel<<<B / BM, TPB, 0, stream>>>(x, W0t, W1t, out);
    } else {
        kan_fused_kernel<<<B / NTHR, NTHR, 0, stream>>>(
            x, cp0, bw0, sw0, imp0, cp1, bw1, sw1, imp1, out);
    }
}

// Round 5
// 77.728 us; speedup vs baseline: 1.1450x; 1.1450x over previous
//
#include <hip/hip_runtime.h>
#include <math.h>

typedef __attribute__((ext_vector_type(8))) _Float16 f16x8;
typedef __attribute__((ext_vector_type(2))) _Float16 f16x2;
typedef __attribute__((ext_vector_type(4))) float f32x4;

// ============================ MFMA fused kernel v3 ============================
// out[b,j] = sum_k F(b,k) * W(k,j), k = c*64 + i  (c: 0=silu base, 1..5=basis)
// Key change vs v2: W fragments are read DIRECTLY FROM GLOBAL (L2-resident,
// 192KB) into registers -- no W LDS staging, no in-loop barriers. LDS holds
// only F (XOR-swizzled) + H. Each wave owns a disjoint 16-row strip and the
// full output width, so F is read exactly once per pass.

#define TPB 256
#define BM  64

#define F_OFF   0                      // F: 64 rows x 768B (swizzled) = 49152
#define HSTRIDE 272                    // 128 cols x 2B + 16B pad
#define H_OFF   49152                  // H: 64 x 272 = 17408
#define LDS_TOT (49152 + 64 * HSTRIDE) // 66560 B -> 2 blocks/CU

__global__ __launch_bounds__(TPB, 2) void kan_mfma_kernel(
    const float* __restrict__ x, const _Float16* __restrict__ W0t,
    const _Float16* __restrict__ W1t, float* __restrict__ out)
{
    __shared__ char smem[LDS_TOT];
    const int tid  = threadIdx.x;
    const int lane = tid & 63;
    const int wid  = tid >> 6;          // 4 waves, disjoint 16-row strips
    const int gq   = lane >> 4;         // k-group 0..3
    const int lm   = lane & 15;
    const int wavebase = wid * 16;
    const long rowbase = (long)blockIdx.x * BM;

    // --- basis table -> piecewise-linear consts (computed per thread, exact) ---
    float FS0[5], FB0[5], FS1[5], FB1[5];
    {
        float bvv[3][5];
        #pragma unroll
        for (int g = 0; g < 3; ++g) {
            float gv = (float)g - 1.0f;
            float e[5]; float s = 0.f;
            #pragma unroll
            for (int i = 0; i < 5; ++i) {
                float cc = -0.8125f + 0.325f * (float)i;   // (knots[i+1]+knots[i+2])/2
                float d  = (gv - cc) * (1.0f / 0.65f);     // width 0.65
                e[i] = __expf(-d * d); s += e[i];
            }
            float inv = 1.0f / (s + 1e-6f);
            #pragma unroll
            for (int i = 0; i < 5; ++i) bvv[g][i] = e[i] * inv;
        }
        #pragma unroll
        for (int c = 0; c < 5; ++c) {
            FS0[c] = bvv[1][c] - bvv[0][c];  FB0[c] = bvv[0][c];
            FS1[c] = bvv[2][c] - bvv[1][c];  FB1[c] = 2.f * bvv[1][c] - bvv[2][c];
        }
    }

    auto feats6 = [&](float v, float* f) {
        float sg = 1.0f / (1.0f + __expf(-v));
        f[0] = v * sg;
        float gi = fminf(fmaxf(v, -1.f), 1.f) + 1.f;   // [0,2]
        bool s1 = gi >= 1.0f;
        #pragma unroll
        for (int c = 0; c < 5; ++c)
            f[c + 1] = fmaf(gi, s1 ? FS1[c] : FS0[c], s1 ? FB1[c] : FB0[c]);
    };

    // build features for 8 consecutive i of one row; write 6x ds_write_b128.
    // conflict-free: bank group 4*((l&7)^(l>>3)), 8 lanes each (= minimum).
    auto buildF8 = [&](int r, int io, const float* v) {
        f16x8 vc[6];
        #pragma unroll
        for (int e = 0; e < 8; ++e) {
            float f[6];
            feats6(v[e], f);
            #pragma unroll
            for (int c = 0; c < 6; ++c) vc[c][e] = (_Float16)f[c];
        }
        const int swz = (r & 7) << 4;
        #pragma unroll
        for (int c = 0; c < 6; ++c)
            *(f16x8*)(smem + F_OFF + ((r * 768 + c * 128 + io * 2) ^ swz)) = vc[c];
    };

    // ---------------- build F0 from x (coalesced 32B per thread-iter) ----------------
    #pragma unroll
    for (int p = 0; p < 2; ++p) {
        int idx = tid + p * TPB;            // 0..511 : 64 rows x 8 groups
        int r = idx >> 3, io = (idx & 7) * 8;
        const float* xp = x + (rowbase + r) * 64 + io;
        float4 xa = *(const float4*)(xp);
        float4 xb = *(const float4*)(xp + 4);
        float v[8] = {xa.x, xa.y, xa.z, xa.w, xb.x, xb.y, xb.z, xb.w};
        buildF8(r, io, v);
    }
    __syncthreads();

    // ---------------- pass 0: h[16 rows/wave][128 cols], K=384 ----------------
    f32x4 acc[8] = {};
    {
        const char* w0 = (const char*)W0t + gq * 2048 + lm * 16;
        const int arow  = wavebase + lm;
        const int abase = arow * 768 + gq * 16;
        const int aswz  = (arow & 7) << 4;
        f16x8 bc[8], bn[8], ac, an;
        #pragma unroll
        for (int nf = 0; nf < 8; ++nf) bc[nf] = *(const f16x8*)(w0 + nf * 256);
        ac = *(const f16x8*)(smem + F_OFF + (abase ^ aswz));
        #pragma unroll
        for (int s = 0; s < 12; ++s) {
            if (s < 11) {
                #pragma unroll
                for (int nf = 0; nf < 8; ++nf)
                    bn[nf] = *(const f16x8*)(w0 + (s + 1) * 8192 + nf * 256);
                an = *(const f16x8*)(smem + F_OFF + ((abase + (s + 1) * 64) ^ aswz));
            }
            #pragma unroll
            for (int nf = 0; nf < 8; ++nf)
                acc[nf] = __builtin_amdgcn_mfma_f32_16x16x32_f16(ac, bc[nf], acc[nf], 0, 0, 0);
            if (s < 11) {
                #pragma unroll
                for (int nf = 0; nf < 8; ++nf) bc[nf] = bn[nf];
                ac = an;
            }
        }
    }

    // h -> H LDS f16 (C/D layout: row = gq*4+rg, col = lm within 16x16 tile)
    #pragma unroll
    for (int nf = 0; nf < 8; ++nf)
        #pragma unroll
        for (int rg = 0; rg < 4; ++rg)
            *(_Float16*)(smem + H_OFF + (wavebase + gq * 4 + rg) * HSTRIDE
                         + (nf * 16 + lm) * 2) = (_Float16)acc[nf][rg];
    __syncthreads();                        // pass0 F-reads + H-writes complete

    // ---------------- passes 1,2: out[16/wave][64], K=2x384 ----------------
    f32x4 accO[4] = {};
    #pragma unroll
    for (int half = 0; half < 2; ++half) {
        // rebuild F from h[:, half*64 .. half*64+64]
        #pragma unroll
        for (int p = 0; p < 2; ++p) {
            int idx = tid + p * TPB;
            int r = idx >> 3, io = (idx & 7) * 8;
            f16x8 hv = *(const f16x8*)(smem + H_OFF + r * HSTRIDE + half * 128 + io * 2);
            float v[8];
            #pragma unroll
            for (int e = 0; e < 8; ++e) v[e] = (float)hv[e];
            buildF8(r, io, v);
        }
        __syncthreads();                    // F rebuilt

        const char* w1 = (const char*)W1t + half * 49152 + gq * 1024 + lm * 16;
        const int arow  = wavebase + lm;
        const int abase = arow * 768 + gq * 16;
        const int aswz  = (arow & 7) << 4;
        f16x8 bc[4], bn[4], ac, an;
        #pragma unroll
        for (int nf = 0; nf < 4; ++nf) bc[nf] = *(const f16x8*)(w1 + nf * 256);
        ac = *(const f16x8*)(smem + F_OFF + (abase ^ aswz));
        #pragma unroll
        for (int s = 0; s < 12; ++s) {
            if (s < 11) {
                #pragma unroll
                for (int nf = 0; nf < 4; ++nf)
                    bn[nf] = *(const f16x8*)(w1 + (s + 1) * 4096 + nf * 256);
                an = *(const f16x8*)(smem + F_OFF + ((abase + (s + 1) * 64) ^ aswz));
            }
            #pragma unroll
            for (int nf = 0; nf < 4; ++nf)
                accO[nf] = __builtin_amdgcn_mfma_f32_16x16x32_f16(ac, bc[nf], accO[nf], 0, 0, 0);
            if (s < 11) {
                #pragma unroll
                for (int nf = 0; nf < 4; ++nf) bc[nf] = bn[nf];
                ac = an;
            }
        }
        if (half == 0) __syncthreads();     // pass1 F-reads done before rebuild
    }

    // ---------------- store out ----------------
    float* og = out + (rowbase + wavebase) * 64;
    #pragma unroll
    for (int nf = 0; nf < 4; ++nf)
        #pragma unroll
        for (int rg = 0; rg < 4; ++rg)
            og[(gq * 4 + rg) * 64 + nf * 16 + lm] = accO[nf][rg];
}

// ------------- pre-kernel: combine imp/bw/sw/cp -> tiled f16 weights -------------
// W0t flat f = ((kt*4+g)*128 + n)*8 + e ; k = kt*32+g*8+e ; c=k>>6 ; i=k&63
// W1t flat f = (((half*12+kt)*4+g)*64 + n)*8 + e ; i2 = (k&63)+half*64
__global__ __launch_bounds__(256) void kan_combine_w(
    const float* __restrict__ cp0, const float* __restrict__ bw0,
    const float* __restrict__ sw0, const float* __restrict__ imp0,
    const float* __restrict__ cp1, const float* __restrict__ bw1,
    const float* __restrict__ sw1, const float* __restrict__ imp1,
    _Float16* __restrict__ W0t, _Float16* __restrict__ W1t)
{
    int f = blockIdx.x * 256 + threadIdx.x;
    if (f < 49152) {
        int e = f & 7, n = (f >> 3) & 127, g = (f >> 10) & 3, kt = f >> 12;
        int k = kt * 32 + g * 8 + e, c = k >> 6, i = k & 63;
        int edge = i * 128 + n;
        float w = imp0[edge] * ((c == 0) ? bw0[edge] : sw0[edge] * cp0[edge * 5 + (c - 1)]);
        W0t[f] = (_Float16)w;
    } else {
        int f2 = f - 49152;
        int e = f2 & 7, n = (f2 >> 3) & 63, g = (f2 >> 9) & 3;
        int q = f2 >> 11;                 // 0..23
        int half = q / 12, kt = q - half * 12;
        int kl = kt * 32 + g * 8 + e, c = kl >> 6;
        int i2 = (kl & 63) + half * 64;
        int edge = i2 * 64 + n;
        float w = imp1[edge] * ((c == 0) ? bw1[edge] : sw1[edge] * cp1[edge * 5 + (c - 1)]);
        W1t[f2] = (_Float16)w;
    }
}

// ===================== fallback: proven fp32 kernel (round 2) =====================
#define NTHR 256
#define JT 32
#define WS8 8

#define STAGE_L0(JBASE) do {                                                  \
    _Pragma("unroll")                                                         \
    for (int p = 0; p < 8; ++p) {                                             \
        int idx = tid + p * NTHR;                                             \
        int i  = idx >> 5;                                                    \
        int jj = idx & 31;                                                    \
        int e  = i * 128 + (JBASE) + jj;                                      \
        float im = imp0[e];                                                   \
        float wb = bw0[e] * im;                                               \
        float ws = sw0[e] * im;                                               \
        const float* cp = cp0 + e * 5;                                        \
        float* wp = wbuf + idx * WS8;                                         \
        wp[0] = wb;                                                           \
        wp[1] = ws * cp[0]; wp[2] = ws * cp[1]; wp[3] = ws * cp[2];           \
        wp[4] = ws * cp[3]; wp[5] = ws * cp[4];                               \
    }                                                                         \
} while (0)

#define STAGE_L1(IBASE, JBASE) do {                                           \
    _Pragma("unroll")                                                         \
    for (int p = 0; p < 8; ++p) {                                             \
        int idx = tid + p * NTHR;                                             \
        int ii = idx >> 5;                                                    \
        int jj = idx & 31;                                                    \
        int e  = ((IBASE) + ii) * 64 + (JBASE) + jj;                          \
        float im = imp1[e];                                                   \
        float wb = bw1[e] * im;                                               \
        float ws = sw1[e] * im;                                               \
        const float* cp = cp1 + e * 5;                                        \
        float* wp = wbuf + idx * WS8;                                         \
        wp[0] = wb;                                                           \
        wp[1] = ws * cp[0]; wp[2] = ws * cp[1]; wp[3] = ws * cp[2];           \
        wp[4] = ws * cp[3]; wp[5] = ws * cp[4];                               \
    }                                                                         \
} while (0)

#define COMPUTE_TILE(ACC) do {                                                \
    _Pragma("unroll 2")                                                       \
    for (int i = 0; i < 64; ++i) {                                            \
        float v  = vbuf[i][tid];                                              \
        float sg = 1.0f / (1.0f + __expf(-v));                                \
        float base = v * sg;                                                  \
        float xc = fminf(fmaxf(v, -1.0f), 1.0f);                              \
        float gi = xc + 1.0f;                                                 \
        int lo = (int)gi; lo = (lo > 2) ? 2 : lo;                             \
        float fr = gi - (float)lo;                                            \
        int hi = (fr > 0.0f) ? (lo + 1) : lo;                                 \
        float b0 = bvt[lo][0]; b0 += (bvt[hi][0] - b0) * fr;                  \
        float b1 = bvt[lo][1]; b1 += (bvt[hi][1] - b1) * fr;                  \
        float b2 = bvt[lo][2]; b2 += (bvt[hi][2] - b2) * fr;                  \
        float b3 = bvt[lo][3]; b3 += (bvt[hi][3] - b3) * fr;                  \
        float b4 = bvt[lo][4]; b4 += (bvt[hi][4] - b4) * fr;                  \
        const float* wr = wbuf + i * (JT * WS8);                              \
        _Pragma("unroll")                                                     \
        for (int jj = 0; jj < JT; ++jj) {                                     \
            const float* wp = wr + jj * WS8;                                  \
            float a = ACC[jj];                                                \
            a = fmaf(wp[0], base, a);                                         \
            a = fmaf(wp[1], b0, a);                                           \
            a = fmaf(wp[2], b1, a);                                           \
            a = fmaf(wp[3], b2, a);                                           \
            a = fmaf(wp[4], b3, a);                                           \
            a = fmaf(wp[5], b4, a);                                           \
            ACC[jj] = a;                                                      \
        }                                                                     \
    }                                                                         \
} while (0)

__global__ __launch_bounds__(NTHR) void kan_fused_kernel(
    const float* __restrict__ x,
    const float* __restrict__ cp0, const float* __restrict__ bw0,
    const float* __restrict__ sw0, const float* __restrict__ imp0,
    const float* __restrict__ cp1, const float* __restrict__ bw1,
    const float* __restrict__ sw1, const float* __restrict__ imp1,
    float* __restrict__ out)
{
    __shared__ float vbuf[64][NTHR + 1];
    __shared__ float wbuf[64 * JT * WS8];
    __shared__ float bvt[3][8];

    const int tid = threadIdx.x;

    if (tid < 3) {
        float gv = -1.0f + (float)tid;
        float e[5];
        float s = 0.0f;
        #pragma unroll
        for (int i = 0; i < 5; ++i) {
            float c = -0.8125f + 0.325f * (float)i;
            float d = (gv - c) * (1.0f / 0.65f);
            e[i] = expf(-d * d);
            s += e[i];
        }
        float inv = 1.0f / (s + 1e-6f);
        #pragma unroll
        for (int i = 0; i < 5; ++i) bvt[tid][i] = e[i] * inv;
    }

    {
        const float4* xg = (const float4*)(x + (size_t)blockIdx.x * (NTHR * 64));
        #pragma unroll
        for (int it = 0; it < 16; ++it) {
            int e4 = tid + it * NTHR;
            float4 v = xg[e4];
            int r  = e4 >> 4;
            int ib = (e4 & 15) << 2;
            vbuf[ib + 0][r] = v.x;
            vbuf[ib + 1][r] = v.y;
            vbuf[ib + 2][r] = v.z;
            vbuf[ib + 3][r] = v.w;
        }
    }
    __syncthreads();

    float h0[32] = {}, h1[32] = {}, h2[32] = {}, h3[32] = {};
    STAGE_L0(0);   __syncthreads(); COMPUTE_TILE(h0); __syncthreads();
    STAGE_L0(32);  __syncthreads(); COMPUTE_TILE(h1); __syncthreads();
    STAGE_L0(64);  __syncthreads(); COMPUTE_TILE(h2); __syncthreads();
    STAGE_L0(96);  __syncthreads(); COMPUTE_TILE(h3); __syncthreads();

    #pragma unroll
    for (int i = 0; i < 32; ++i) vbuf[i][tid] = h0[i];
    #pragma unroll
    for (int i = 0; i < 32; ++i) vbuf[32 + i][tid] = h1[i];

    float o0[32] = {}, o1[32] = {};
    STAGE_L1(0, 0);   __syncthreads(); COMPUTE_TILE(o0); __syncthreads();
    STAGE_L1(0, 32);  __syncthreads(); COMPUTE_TILE(o1); __syncthreads();

    #pragma unroll
    for (int i = 0; i < 32; ++i) vbuf[i][tid] = h2[i];
    #pragma unroll
    for (int i = 0; i < 32; ++i) vbuf[32 + i][tid] = h3[i];

    STAGE_L1(64, 0);  __syncthreads(); COMPUTE_TILE(o0); __syncthreads();
    STAGE_L1(64, 32); __syncthreads(); COMPUTE_TILE(o1);

    float4* og = (float4*)(out + (size_t)blockIdx.x * (NTHR * 64) + (size_t)tid * 64);
    #pragma unroll
    for (int q = 0; q < 8; ++q)
        og[q] = make_float4(o0[4 * q + 0], o0[4 * q + 1], o0[4 * q + 2], o0[4 * q + 3]);
    #pragma unroll
    for (int q = 0; q < 8; ++q)
        og[8 + q] = make_float4(o1[4 * q + 0], o1[4 * q + 1], o1[4 * q + 2], o1[4 * q + 3]);
}

// =================================== launch ===================================
extern "C" void kernel_launch(void* const* d_in, const int* in_sizes, int n_in,
                              void* d_out, int out_size, void* d_ws, size_t ws_size,
                              hipStream_t stream) {
    const float* x    = (const float*)d_in[0];
    const float* cp0  = (const float*)d_in[1];
    const float* bw0  = (const float*)d_in[2];
    const float* sw0  = (const float*)d_in[3];
    const float* imp0 = (const float*)d_in[4];
    const float* cp1  = (const float*)d_in[5];
    const float* bw1  = (const float*)d_in[6];
    const float* sw1  = (const float*)d_in[7];
    const float* imp1 = (const float*)d_in[8];
    float* out = (float*)d_out;

    const int B = in_sizes[0] / 64;                 // 131072
    const size_t need = 98304 * sizeof(_Float16);   // 192 KB combined weights

    if (ws_size >= need && (B % BM) == 0) {
        _Float16* W0t = (_Float16*)d_ws;
        _Float16* W1t = W0t + 49152;
        kan_combine_w<<<384, 256, 0, stream>>>(cp0, bw0, sw0, imp0,
                                               cp1, bw1, sw1, imp1, W0t, W1t);
        kan_mfma_kernel<<<B / BM, TPB, 0, stream>>>(x, W0t, W1t, out);
    } else {
        kan_fused_kernel<<<B / NTHR, NTHR, 0, stream>>>(
            x, cp0, bw0, sw0, imp0, cp1, bw1, sw1, imp1, out);
    }
}

// Round 6
// 67.377 us; speedup vs baseline: 1.3209x; 1.1536x over previous
//
#include <hip/hip_runtime.h>
#include <math.h>

typedef __attribute__((ext_vector_type(8))) _Float16 f16x8;
typedef __attribute__((ext_vector_type(2))) _Float16 f16x2;
typedef __attribute__((ext_vector_type(4))) float f32x4;

// ============================ MFMA fused kernel v4 ============================
// out[b,j] = sum_k F(b,k) * W(k,j), k = c*64 + i  (c: 0=silu base, 1..5=basis)
// v4: A-fragments are computed DIRECTLY IN REGISTERS. MFMA A-layout for
// 16x16x32 (verified by v2/v3 passing): lane (gq,lm) holds A[row=lm][k=gq*8..+7].
// With k=c*64+i, step s needs i=(s&1)*32+gq*8..+7, c=s>>1 -- 8 consecutive i of
// the lane's OWN row. So each lane loads its own x / h values and builds all 6
// features for its two 8-wide i-blocks straight into MFMA fragments.
// No F LDS, no F barriers, no duplicated feature evals. LDS holds only H.

#define TPB 256
#define BM  64
#define HSTRIDE 272                    // 128 cols x 2B + 16B pad (rows shift 16B mod 128)
#define LDS_TOT (64 * HSTRIDE)         // 17408 B

__global__ __launch_bounds__(TPB, 4) void kan_mfma_kernel(
    const float* __restrict__ x, const _Float16* __restrict__ W0t,
    const _Float16* __restrict__ W1t, float* __restrict__ out)
{
    __shared__ char smem[LDS_TOT];
    const int tid  = threadIdx.x;
    const int lane = tid & 63;
    const int wid  = tid >> 6;          // 4 waves, disjoint 16-row strips
    const int gq   = lane >> 4;         // k-group 0..3
    const int lm   = lane & 15;
    const int wavebase = wid * 16;
    const int myrow = wavebase + lm;    // this lane's A-row within the block
    const long rowbase = (long)blockIdx.x * BM;

    // --- basis table -> piecewise-linear consts (computed per thread, exact) ---
    float FS0[5], FB0[5], FS1[5], FB1[5];
    {
        float bvv[3][5];
        #pragma unroll
        for (int g = 0; g < 3; ++g) {
            float gv = (float)g - 1.0f;
            float e[5]; float s = 0.f;
            #pragma unroll
            for (int i = 0; i < 5; ++i) {
                float cc = -0.8125f + 0.325f * (float)i;   // (knots[i+1]+knots[i+2])/2
                float d  = (gv - cc) * (1.0f / 0.65f);     // width 0.65
                e[i] = __expf(-d * d); s += e[i];
            }
            float inv = 1.0f / (s + 1e-6f);
            #pragma unroll
            for (int i = 0; i < 5; ++i) bvv[g][i] = e[i] * inv;
        }
        #pragma unroll
        for (int c = 0; c < 5; ++c) {
            FS0[c] = bvv[1][c] - bvv[0][c];  FB0[c] = bvv[0][c];
            FS1[c] = bvv[2][c] - bvv[1][c];  FB1[c] = 2.f * bvv[1][c] - bvv[2][c];
        }
    }

    auto feats6 = [&](float v, float* f) {
        float sg = 1.0f / (1.0f + __expf(-v));
        f[0] = v * sg;
        float gi = fminf(fmaxf(v, -1.f), 1.f) + 1.f;   // [0,2]
        bool s1 = gi >= 1.0f;
        #pragma unroll
        for (int c = 0; c < 5; ++c)
            f[c + 1] = fmaf(gi, s1 ? FS1[c] : FS0[c], s1 ? FB1[c] : FB0[c]);
    };

#if __has_builtin(__builtin_amdgcn_cvt_pkrtz)
    auto pk2 = [](float a, float b) -> f16x2 {
        return (f16x2)__builtin_amdgcn_cvt_pkrtz(a, b);
    };
#else
    auto pk2 = [](float a, float b) -> f16x2 {
        return f16x2{(_Float16)a, (_Float16)b};
    };
#endif

    // build all 6 feature fragments for 8 values (pairwise, packed via cvt_pk)
    auto buildFeats = [&](const float* v, f16x8* dst) {
        union U { f16x8 v8; f16x2 h2[4]; } u[6];
        #pragma unroll
        for (int q = 0; q < 4; ++q) {
            float fa[6], fb[6];
            feats6(v[2 * q], fa);
            feats6(v[2 * q + 1], fb);
            #pragma unroll
            for (int c = 0; c < 6; ++c) u[c].h2[q] = pk2(fa[c], fb[c]);
        }
        #pragma unroll
        for (int c = 0; c < 6; ++c) dst[c] = u[c].v8;
    };

    // ---------------- pass 0: A-feats from x, straight to registers ----------------
    f16x8 fA[2][6];                     // [ihalf][feature c]
    {
        const float* xp = x + (rowbase + myrow) * 64 + gq * 8;
        float4 a0 = *(const float4*)(xp);
        float4 a1 = *(const float4*)(xp + 4);
        float4 a2 = *(const float4*)(xp + 32);
        float4 a3 = *(const float4*)(xp + 36);
        float v0[8] = {a0.x, a0.y, a0.z, a0.w, a1.x, a1.y, a1.z, a1.w};
        float v1[8] = {a2.x, a2.y, a2.z, a2.w, a3.x, a3.y, a3.z, a3.w};
        buildFeats(v0, fA[0]);
        buildFeats(v1, fA[1]);
    }

    // h[16 rows/wave][128 cols], K=384
    f32x4 acc[8] = {};
    {
        const char* w0 = (const char*)W0t + gq * 2048 + lm * 16;
        #pragma unroll
        for (int s = 0; s < 12; ++s) {
            f16x8 a = fA[s & 1][s >> 1];
            #pragma unroll
            for (int nf = 0; nf < 8; ++nf) {
                f16x8 b = *(const f16x8*)(w0 + s * 8192 + nf * 256);
                acc[nf] = __builtin_amdgcn_mfma_f32_16x16x32_f16(a, b, acc[nf], 0, 0, 0);
            }
        }
    }

    // h -> H LDS f16 (C/D layout: row = gq*4+rg, col = nf*16+lm)
    #pragma unroll
    for (int nf = 0; nf < 8; ++nf)
        #pragma unroll
        for (int rg = 0; rg < 4; ++rg)
            *(_Float16*)(smem + (wavebase + gq * 4 + rg) * HSTRIDE
                         + (nf * 16 + lm) * 2) = (_Float16)acc[nf][rg];
    __syncthreads();

    // ---------------- layer 1: out[16/wave][64], K=2x384 over i2 halves ----------------
    f32x4 accO[4] = {};
    #pragma unroll
    for (int half = 0; half < 2; ++half) {
        f16x8 fB[2][6];
        #pragma unroll
        for (int ih = 0; ih < 2; ++ih) {
            f16x8 hv = *(const f16x8*)(smem + myrow * HSTRIDE
                                       + (half * 64 + ih * 32 + gq * 8) * 2);
            float v[8];
            #pragma unroll
            for (int e = 0; e < 8; ++e) v[e] = (float)hv[e];
            buildFeats(v, fB[ih]);
        }
        const char* w1 = (const char*)W1t + half * 49152 + gq * 1024 + lm * 16;
        #pragma unroll
        for (int s = 0; s < 12; ++s) {
            f16x8 a = fB[s & 1][s >> 1];
            #pragma unroll
            for (int nf = 0; nf < 4; ++nf) {
                f16x8 b = *(const f16x8*)(w1 + s * 4096 + nf * 256);
                accO[nf] = __builtin_amdgcn_mfma_f32_16x16x32_f16(a, b, accO[nf], 0, 0, 0);
            }
        }
    }

    // ---------------- store out ----------------
    float* og = out + (rowbase + wavebase) * 64;
    #pragma unroll
    for (int nf = 0; nf < 4; ++nf)
        #pragma unroll
        for (int rg = 0; rg < 4; ++rg)
            og[(gq * 4 + rg) * 64 + nf * 16 + lm] = accO[nf][rg];
}

// ------------- pre-kernel: combine imp/bw/sw/cp -> tiled f16 weights -------------
// W0t flat f = ((kt*4+g)*128 + n)*8 + e ; k = kt*32+g*8+e ; c=k>>6 ; i=k&63
// W1t flat f = (((half*12+kt)*4+g)*64 + n)*8 + e ; i2 = (k&63)+half*64
__global__ __launch_bounds__(256) void kan_combine_w(
    const float* __restrict__ cp0, const float* __restrict__ bw0,
    const float* __restrict__ sw0, const float* __restrict__ imp0,
    const float* __restrict__ cp1, const float* __restrict__ bw1,
    const float* __restrict__ sw1, const float* __restrict__ imp1,
    _Float16* __restrict__ W0t, _Float16* __restrict__ W1t)
{
    int f = blockIdx.x * 256 + threadIdx.x;
    if (f < 49152) {
        int e = f & 7, n = (f >> 3) & 127, g = (f >> 10) & 3, kt = f >> 12;
        int k = kt * 32 + g * 8 + e, c = k >> 6, i = k & 63;
        int edge = i * 128 + n;
        float w = imp0[edge] * ((c == 0) ? bw0[edge] : sw0[edge] * cp0[edge * 5 + (c - 1)]);
        W0t[f] = (_Float16)w;
    } else {
        int f2 = f - 49152;
        int e = f2 & 7, n = (f2 >> 3) & 63, g = (f2 >> 9) & 3;
        int q = f2 >> 11;                 // 0..23
        int half = q / 12, kt = q - half * 12;
        int kl = kt * 32 + g * 8 + e, c = kl >> 6;
        int i2 = (kl & 63) + half * 64;
        int edge = i2 * 64 + n;
        float w = imp1[edge] * ((c == 0) ? bw1[edge] : sw1[edge] * cp1[edge * 5 + (c - 1)]);
        W1t[f2] = (_Float16)w;
    }
}

// ===================== fallback: proven fp32 kernel (round 2) =====================
#define NTHR 256
#define JT 32
#define WS8 8

#define STAGE_L0(JBASE) do {                                                  \
    _Pragma("unroll")                                                         \
    for (int p = 0; p < 8; ++p) {                                             \
        int idx = tid + p * NTHR;                                             \
        int i  = idx >> 5;                                                    \
        int jj = idx & 31;                                                    \
        int e  = i * 128 + (JBASE) + jj;                                      \
        float im = imp0[e];                                                   \
        float wb = bw0[e] * im;                                               \
        float ws = sw0[e] * im;                                               \
        const float* cp = cp0 + e * 5;                                        \
        float* wp = wbuf + idx * WS8;                                         \
        wp[0] = wb;                                                           \
        wp[1] = ws * cp[0]; wp[2] = ws * cp[1]; wp[3] = ws * cp[2];           \
        wp[4] = ws * cp[3]; wp[5] = ws * cp[4];                               \
    }                                                                         \
} while (0)

#define STAGE_L1(IBASE, JBASE) do {                                           \
    _Pragma("unroll")                                                         \
    for (int p = 0; p < 8; ++p) {                                             \
        int idx = tid + p * NTHR;                                             \
        int ii = idx >> 5;                                                    \
        int jj = idx & 31;                                                    \
        int e  = ((IBASE) + ii) * 64 + (JBASE) + jj;                          \
        float im = imp1[e];                                                   \
        float wb = bw1[e] * im;                                               \
        float ws = sw1[e] * im;                                               \
        const float* cp = cp1 + e * 5;                                        \
        float* wp = wbuf + idx * WS8;                                         \
        wp[0] = wb;                                                           \
        wp[1] = ws * cp[0]; wp[2] = ws * cp[1]; wp[3] = ws * cp[2];           \
        wp[4] = ws * cp[3]; wp[5] = ws * cp[4];                               \
    }                                                                         \
} while (0)

#define COMPUTE_TILE(ACC) do {                                                \
    _Pragma("unroll 2")                                                       \
    for (int i = 0; i < 64; ++i) {                                            \
        float v  = vbuf[i][tid];                                              \
        float sg = 1.0f / (1.0f + __expf(-v));                                \
        float base = v * sg;                                                  \
        float xc = fminf(fmaxf(v, -1.0f), 1.0f);                              \
        float gi = xc + 1.0f;                                                 \
        int lo = (int)gi; lo = (lo > 2) ? 2 : lo;                             \
        float fr = gi - (float)lo;                                            \
        int hi = (fr > 0.0f) ? (lo + 1) : lo;                                 \
        float b0 = bvt[lo][0]; b0 += (bvt[hi][0] - b0) * fr;                  \
        float b1 = bvt[lo][1]; b1 += (bvt[hi][1] - b1) * fr;                  \
        float b2 = bvt[lo][2]; b2 += (bvt[hi][2] - b2) * fr;                  \
        float b3 = bvt[lo][3]; b3 += (bvt[hi][3] - b3) * fr;                  \
        float b4 = bvt[lo][4]; b4 += (bvt[hi][4] - b4) * fr;                  \
        const float* wr = wbuf + i * (JT * WS8);                              \
        _Pragma("unroll")                                                     \
        for (int jj = 0; jj < JT; ++jj) {                                     \
            const float* wp = wr + jj * WS8;                                  \
            float a = ACC[jj];                                                \
            a = fmaf(wp[0], base, a);                                         \
            a = fmaf(wp[1], b0, a);                                           \
            a = fmaf(wp[2], b1, a);                                           \
            a = fmaf(wp[3], b2, a);                                           \
            a = fmaf(wp[4], b3, a);                                           \
            a = fmaf(wp[5], b4, a);                                           \
            ACC[jj] = a;                                                      \
        }                                                                     \
    }                                                                         \
} while (0)

__global__ __launch_bounds__(NTHR) void kan_fused_kernel(
    const float* __restrict__ x,
    const float* __restrict__ cp0, const float* __restrict__ bw0,
    const float* __restrict__ sw0, const float* __restrict__ imp0,
    const float* __restrict__ cp1, const float* __restrict__ bw1,
    const float* __restrict__ sw1, const float* __restrict__ imp1,
    float* __restrict__ out)
{
    __shared__ float vbuf[64][NTHR + 1];
    __shared__ float wbuf[64 * JT * WS8];
    __shared__ float bvt[3][8];

    const int tid = threadIdx.x;

    if (tid < 3) {
        float gv = -1.0f + (float)tid;
        float e[5];
        float s = 0.0f;
        #pragma unroll
        for (int i = 0; i < 5; ++i) {
            float c = -0.8125f + 0.325f * (float)i;
            float d = (gv - c) * (1.0f / 0.65f);
            e[i] = expf(-d * d);
            s += e[i];
        }
        float inv = 1.0f / (s + 1e-6f);
        #pragma unroll
        for (int i = 0; i < 5; ++i) bvt[tid][i] = e[i] * inv;
    }

    {
        const float4* xg = (const float4*)(x + (size_t)blockIdx.x * (NTHR * 64));
        #pragma unroll
        for (int it = 0; it < 16; ++it) {
            int e4 = tid + it * NTHR;
            float4 v = xg[e4];
            int r  = e4 >> 4;
            int ib = (e4 & 15) << 2;
            vbuf[ib + 0][r] = v.x;
            vbuf[ib + 1][r] = v.y;
            vbuf[ib + 2][r] = v.z;
            vbuf[ib + 3][r] = v.w;
        }
    }
    __syncthreads();

    float h0[32] = {}, h1[32] = {}, h2[32] = {}, h3[32] = {};
    STAGE_L0(0);   __syncthreads(); COMPUTE_TILE(h0); __syncthreads();
    STAGE_L0(32);  __syncthreads(); COMPUTE_TILE(h1); __syncthreads();
    STAGE_L0(64);  __syncthreads(); COMPUTE_TILE(h2); __syncthreads();
    STAGE_L0(96);  __syncthreads(); COMPUTE_TILE(h3); __syncthreads();

    #pragma unroll
    for (int i = 0; i < 32; ++i) vbuf[i][tid] = h0[i];
    #pragma unroll
    for (int i = 0; i < 32; ++i) vbuf[32 + i][tid] = h1[i];

    float o0[32] = {}, o1[32] = {};
    STAGE_L1(0, 0);   __syncthreads(); COMPUTE_TILE(o0); __syncthreads();
    STAGE_L1(0, 32);  __syncthreads(); COMPUTE_TILE(o1); __syncthreads();

    #pragma unroll
    for (int i = 0; i < 32; ++i) vbuf[i][tid] = h2[i];
    #pragma unroll
    for (int i = 0; i < 32; ++i) vbuf[32 + i][tid] = h3[i];

    STAGE_L1(64, 0);  __syncthreads(); COMPUTE_TILE(o0); __syncthreads();
    STAGE_L1(64, 32); __syncthreads(); COMPUTE_TILE(o1);

    float4* og = (float4*)(out + (size_t)blockIdx.x * (NTHR * 64) + (size_t)tid * 64);
    #pragma unroll
    for (int q = 0; q < 8; ++q)
        og[q] = make_float4(o0[4 * q + 0], o0[4 * q + 1], o0[4 * q + 2], o0[4 * q + 3]);
    #pragma unroll
    for (int q = 0; q < 8; ++q)
        og[8 + q] = make_float4(o1[4 * q + 0], o1[4 * q + 1], o1[4 * q + 2], o1[4 * q + 3]);
}

// =================================== launch ===================================
extern "C" void kernel_launch(void* const* d_in, const int* in_sizes, int n_in,
                              void* d_out, int out_size, void* d_ws, size_t ws_size,
                              hipStream_t stream) {
    const float* x    = (const float*)d_in[0];
    const float* cp0  = (const float*)d_in[1];
    const float* bw0  = (const float*)d_in[2];
    const float* sw0  = (const float*)d_in[3];
    const float* imp0 = (const float*)d_in[4];
    const float* cp1  = (const float*)d_in[5];
    const float* bw1  = (const float*)d_in[6];
    const float* sw1  = (const float*)d_in[7];
    const float* imp1 = (const float*)d_in[8];
    float* out = (float*)d_out;

    const int B = in_sizes[0] / 64;                 // 131072
    const size_t need = 98304 * sizeof(_Float16);   // 192 KB combined weights

    if (ws_size >= need && (B % BM) == 0) {
        _Float16* W0t = (_Float16*)d_ws;
        _Float16* W1t = W0t + 49152;
        kan_combine_w<<<384, 256, 0, stream>>>(cp0, bw0, sw0, imp0,
                                               cp1, bw1, sw1, imp1, W0t, W1t);
        kan_mfma_kernel<<<B / BM, TPB, 0, stream>>>(x, W0t, W1t, out);
    } else {
        kan_fused_kernel<<<B / NTHR, NTHR, 0, stream>>>(
            x, cp0, bw0, sw0, imp0, cp1, bw1, sw1, imp1, out);
    }
}

// Round 7
// 52.978 us; speedup vs baseline: 1.6800x; 1.2718x over previous
//
#include <hip/hip_runtime.h>
#include <math.h>

typedef __attribute__((ext_vector_type(8))) _Float16 f16x8;
typedef __attribute__((ext_vector_type(2))) _Float16 f16x2;
typedef __attribute__((ext_vector_type(4))) float f32x4;

// ============================ MFMA fused kernel v5 ============================
// v5 changes vs v4 (67 µs):
//  - launch_bounds(256,2): v4's (256,4) capped VGPR~64 and made the compiler
//    REMATERIALIZE feature math inside the MFMA loop (VGPR_Count=52, VALUBusy
//    45% = ~3x the hand-counted feature cost). Now fragments stay live.
//  - BM=128, 32 rows/wave (mi=2): each wave streams all of W per block; B
//    traffic per CU halves (6.1MB -> 3.1MB), halving the ~40us L1-stream floor.
//  - explicit B register double-buffer (b0/b1 alternate per unrolled step).

#define TPB 256
#define BM  128
#define HSTRIDE 272                    // 128 cols x 2B + 16B pad
#define LDS_TOT (128 * HSTRIDE)        // 34816 B

__global__ __launch_bounds__(TPB, 2) void kan_mfma_kernel(
    const float* __restrict__ x, const _Float16* __restrict__ W0t,
    const _Float16* __restrict__ W1t, float* __restrict__ out)
{
    __shared__ char smem[LDS_TOT];
    const int tid  = threadIdx.x;
    const int lane = tid & 63;
    const int wid  = tid >> 6;          // 4 waves, disjoint 32-row strips
    const int gq   = lane >> 4;         // k-group 0..3
    const int lm   = lane & 15;
    const int wavebase = wid * 32;
    const long rowbase = (long)blockIdx.x * BM;

    // --- basis table -> piecewise-linear consts (computed per thread, exact) ---
    float FS0[5], FB0[5], FS1[5], FB1[5];
    {
        float bvv[3][5];
        #pragma unroll
        for (int g = 0; g < 3; ++g) {
            float gv = (float)g - 1.0f;
            float e[5]; float s = 0.f;
            #pragma unroll
            for (int i = 0; i < 5; ++i) {
                float cc = -0.8125f + 0.325f * (float)i;   // (knots[i+1]+knots[i+2])/2
                float d  = (gv - cc) * (1.0f / 0.65f);     // width 0.65
                e[i] = __expf(-d * d); s += e[i];
            }
            float inv = 1.0f / (s + 1e-6f);
            #pragma unroll
            for (int i = 0; i < 5; ++i) bvv[g][i] = e[i] * inv;
        }
        #pragma unroll
        for (int c = 0; c < 5; ++c) {
            FS0[c] = bvv[1][c] - bvv[0][c];  FB0[c] = bvv[0][c];
            FS1[c] = bvv[2][c] - bvv[1][c];  FB1[c] = 2.f * bvv[1][c] - bvv[2][c];
        }
    }

    auto feats6 = [&](float v, float* f) {
        float sg = 1.0f / (1.0f + __expf(-v));
        f[0] = v * sg;
        float gi = fminf(fmaxf(v, -1.f), 1.f) + 1.f;   // [0,2]
        bool s1 = gi >= 1.0f;
        #pragma unroll
        for (int c = 0; c < 5; ++c)
            f[c + 1] = fmaf(gi, s1 ? FS1[c] : FS0[c], s1 ? FB1[c] : FB0[c]);
    };

#if __has_builtin(__builtin_amdgcn_cvt_pkrtz)
    auto pk2 = [](float a, float b) -> f16x2 {
        return (f16x2)__builtin_amdgcn_cvt_pkrtz(a, b);
    };
#else
    auto pk2 = [](float a, float b) -> f16x2 {
        return f16x2{(_Float16)a, (_Float16)b};
    };
#endif

    // build all 6 feature fragments for 8 values (pairwise, packed via cvt_pk)
    auto buildFeats = [&](const float* v, f16x8* dst) {
        union U { f16x8 v8; f16x2 h2[4]; } u[6];
        #pragma unroll
        for (int q = 0; q < 4; ++q) {
            float fa[6], fb[6];
            feats6(v[2 * q], fa);
            feats6(v[2 * q + 1], fb);
            #pragma unroll
            for (int c = 0; c < 6; ++c) u[c].h2[q] = pk2(fa[c], fb[c]);
        }
        #pragma unroll
        for (int c = 0; c < 6; ++c) dst[c] = u[c].v8;
    };

    // ---------------- A-feats from x, straight to registers ----------------
    f16x8 fA[2][2][6];                  // [mi][ihalf][c]  (96 VGPR)
    #pragma unroll
    for (int mi = 0; mi < 2; ++mi) {
        const float* xp = x + (rowbase + wavebase + mi * 16 + lm) * 64 + gq * 8;
        float4 a0 = *(const float4*)(xp);
        float4 a1 = *(const float4*)(xp + 4);
        float4 a2 = *(const float4*)(xp + 32);
        float4 a3 = *(const float4*)(xp + 36);
        float v0[8] = {a0.x, a0.y, a0.z, a0.w, a1.x, a1.y, a1.z, a1.w};
        float v1[8] = {a2.x, a2.y, a2.z, a2.w, a3.x, a3.y, a3.z, a3.w};
        buildFeats(v0, fA[mi][0]);
        buildFeats(v1, fA[mi][1]);
    }

    // ---------------- layer 0: h[32 rows/wave][128 cols], K=384 ----------------
    f32x4 acc[2][8] = {};
    {
        const char* w0 = (const char*)W0t + gq * 2048 + lm * 16;
        f16x8 b0[8], b1[8];
        #pragma unroll
        for (int nf = 0; nf < 8; ++nf) b0[nf] = *(const f16x8*)(w0 + nf * 256);

#define L0_STEP(S, CUR, NXT) do {                                             \
        if ((S) < 11) {                                                       \
            _Pragma("unroll")                                                 \
            for (int nf = 0; nf < 8; ++nf)                                    \
                NXT[nf] = *(const f16x8*)(w0 + ((S) + 1) * 8192 + nf * 256);  \
        }                                                                     \
        _Pragma("unroll")                                                     \
        for (int mi = 0; mi < 2; ++mi) {                                      \
            f16x8 a = fA[mi][(S) & 1][(S) >> 1];                              \
            _Pragma("unroll")                                                 \
            for (int nf = 0; nf < 8; ++nf)                                    \
                acc[mi][nf] = __builtin_amdgcn_mfma_f32_16x16x32_f16(         \
                    a, CUR[nf], acc[mi][nf], 0, 0, 0);                        \
        }                                                                     \
    } while (0)

        L0_STEP(0,  b0, b1); L0_STEP(1,  b1, b0);
        L0_STEP(2,  b0, b1); L0_STEP(3,  b1, b0);
        L0_STEP(4,  b0, b1); L0_STEP(5,  b1, b0);
        L0_STEP(6,  b0, b1); L0_STEP(7,  b1, b0);
        L0_STEP(8,  b0, b1); L0_STEP(9,  b1, b0);
        L0_STEP(10, b0, b1); L0_STEP(11, b1, b0);
#undef L0_STEP
    }

    // h -> H LDS f16 (C/D layout: row = gq*4+rg, col = nf*16+lm)
    #pragma unroll
    for (int mi = 0; mi < 2; ++mi)
        #pragma unroll
        for (int nf = 0; nf < 8; ++nf)
            #pragma unroll
            for (int rg = 0; rg < 4; ++rg)
                *(_Float16*)(smem + (wavebase + mi * 16 + gq * 4 + rg) * HSTRIDE
                             + (nf * 16 + lm) * 2) = (_Float16)acc[mi][nf][rg];
    __syncthreads();

    // ---------------- layer 1: out[32/wave][64], K=2x384 over i2 halves ----------------
    f32x4 accO[2][4] = {};
    for (int half = 0; half < 2; ++half) {
        f16x8 fB[2][2][6];
        #pragma unroll
        for (int mi = 0; mi < 2; ++mi)
            #pragma unroll
            for (int ih = 0; ih < 2; ++ih) {
                f16x8 hv = *(const f16x8*)(smem + (wavebase + mi * 16 + lm) * HSTRIDE
                                           + (half * 64 + ih * 32 + gq * 8) * 2);
                float v[8];
                #pragma unroll
                for (int e = 0; e < 8; ++e) v[e] = (float)hv[e];
                buildFeats(v, fB[mi][ih]);
            }

        const char* w1 = (const char*)W1t + half * 49152 + gq * 1024 + lm * 16;
        f16x8 c0[4], c1[4];
        #pragma unroll
        for (int nf = 0; nf < 4; ++nf) c0[nf] = *(const f16x8*)(w1 + nf * 256);

#define L1_STEP(S, CUR, NXT) do {                                             \
        if ((S) < 11) {                                                       \
            _Pragma("unroll")                                                 \
            for (int nf = 0; nf < 4; ++nf)                                    \
                NXT[nf] = *(const f16x8*)(w1 + ((S) + 1) * 4096 + nf * 256);  \
        }                                                                     \
        _Pragma("unroll")                                                     \
        for (int mi = 0; mi < 2; ++mi) {                                      \
            f16x8 a = fB[mi][(S) & 1][(S) >> 1];                              \
            _Pragma("unroll")                                                 \
            for (int nf = 0; nf < 4; ++nf)                                    \
                accO[mi][nf] = __builtin_amdgcn_mfma_f32_16x16x32_f16(        \
                    a, CUR[nf], accO[mi][nf], 0, 0, 0);                       \
        }                                                                     \
    } while (0)

        L1_STEP(0,  c0, c1); L1_STEP(1,  c1, c0);
        L1_STEP(2,  c0, c1); L1_STEP(3,  c1, c0);
        L1_STEP(4,  c0, c1); L1_STEP(5,  c1, c0);
        L1_STEP(6,  c0, c1); L1_STEP(7,  c1, c0);
        L1_STEP(8,  c0, c1); L1_STEP(9,  c1, c0);
        L1_STEP(10, c0, c1); L1_STEP(11, c1, c0);
#undef L1_STEP
    }

    // ---------------- store out ----------------
    float* og = out + (rowbase + wavebase) * 64;
    #pragma unroll
    for (int mi = 0; mi < 2; ++mi)
        #pragma unroll
        for (int nf = 0; nf < 4; ++nf)
            #pragma unroll
            for (int rg = 0; rg < 4; ++rg)
                og[(mi * 16 + gq * 4 + rg) * 64 + nf * 16 + lm] = accO[mi][nf][rg];
}

// ------------- pre-kernel: combine imp/bw/sw/cp -> tiled f16 weights -------------
// W0t flat f = ((kt*4+g)*128 + n)*8 + e ; k = kt*32+g*8+e ; c=k>>6 ; i=k&63
// W1t flat f = (((half*12+kt)*4+g)*64 + n)*8 + e ; i2 = (k&63)+half*64
__global__ __launch_bounds__(256) void kan_combine_w(
    const float* __restrict__ cp0, const float* __restrict__ bw0,
    const float* __restrict__ sw0, const float* __restrict__ imp0,
    const float* __restrict__ cp1, const float* __restrict__ bw1,
    const float* __restrict__ sw1, const float* __restrict__ imp1,
    _Float16* __restrict__ W0t, _Float16* __restrict__ W1t)
{
    int f = blockIdx.x * 256 + threadIdx.x;
    if (f < 49152) {
        int e = f & 7, n = (f >> 3) & 127, g = (f >> 10) & 3, kt = f >> 12;
        int k = kt * 32 + g * 8 + e, c = k >> 6, i = k & 63;
        int edge = i * 128 + n;
        float w = imp0[edge] * ((c == 0) ? bw0[edge] : sw0[edge] * cp0[edge * 5 + (c - 1)]);
        W0t[f] = (_Float16)w;
    } else {
        int f2 = f - 49152;
        int e = f2 & 7, n = (f2 >> 3) & 63, g = (f2 >> 9) & 3;
        int q = f2 >> 11;                 // 0..23
        int half = q / 12, kt = q - half * 12;
        int kl = kt * 32 + g * 8 + e, c = kl >> 6;
        int i2 = (kl & 63) + half * 64;
        int edge = i2 * 64 + n;
        float w = imp1[edge] * ((c == 0) ? bw1[edge] : sw1[edge] * cp1[edge * 5 + (c - 1)]);
        W1t[f2] = (_Float16)w;
    }
}

// ===================== fallback: proven fp32 kernel (round 2) =====================
#define NTHR 256
#define JT 32
#define WS8 8

#define STAGE_L0(JBASE) do {                                                  \
    _Pragma("unroll")                                                         \
    for (int p = 0; p < 8; ++p) {                                             \
        int idx = tid + p * NTHR;                                             \
        int i  = idx >> 5;                                                    \
        int jj = idx & 31;                                                    \
        int e  = i * 128 + (JBASE) + jj;                                      \
        float im = imp0[e];                                                   \
        float wb = bw0[e] * im;                                               \
        float ws = sw0[e] * im;                                               \
        const float* cp = cp0 + e * 5;                                        \
        float* wp = wbuf + idx * WS8;                                         \
        wp[0] = wb;                                                           \
        wp[1] = ws * cp[0]; wp[2] = ws * cp[1]; wp[3] = ws * cp[2];           \
        wp[4] = ws * cp[3]; wp[5] = ws * cp[4];                               \
    }                                                                         \
} while (0)

#define STAGE_L1(IBASE, JBASE) do {                                           \
    _Pragma("unroll")                                                         \
    for (int p = 0; p < 8; ++p) {                                             \
        int idx = tid + p * NTHR;                                             \
        int ii = idx >> 5;                                                    \
        int jj = idx & 31;                                                    \
        int e  = ((IBASE) + ii) * 64 + (JBASE) + jj;                          \
        float im = imp1[e];                                                   \
        float wb = bw1[e] * im;                                               \
        float ws = sw1[e] * im;                                               \
        const float* cp = cp1 + e * 5;                                        \
        float* wp = wbuf + idx * WS8;                                         \
        wp[0] = wb;                                                           \
        wp[1] = ws * cp[0]; wp[2] = ws * cp[1]; wp[3] = ws * cp[2];           \
        wp[4] = ws * cp[3]; wp[5] = ws * cp[4];                               \
    }                                                                         \
} while (0)

#define COMPUTE_TILE(ACC) do {                                                \
    _Pragma("unroll 2")                                                       \
    for (int i = 0; i < 64; ++i) {                                            \
        float v  = vbuf[i][tid];                                              \
        float sg = 1.0f / (1.0f + __expf(-v));                                \
        float base = v * sg;                                                  \
        float xc = fminf(fmaxf(v, -1.0f), 1.0f);                              \
        float gi = xc + 1.0f;                                                 \
        int lo = (int)gi; lo = (lo > 2) ? 2 : lo;                             \
        float fr = gi - (float)lo;                                            \
        int hi = (fr > 0.0f) ? (lo + 1) : lo;                                 \
        float b0 = bvt[lo][0]; b0 += (bvt[hi][0] - b0) * fr;                  \
        float b1 = bvt[lo][1]; b1 += (bvt[hi][1] - b1) * fr;                  \
        float b2 = bvt[lo][2]; b2 += (bvt[hi][2] - b2) * fr;                  \
        float b3 = bvt[lo][3]; b3 += (bvt[hi][3] - b3) * fr;                  \
        float b4 = bvt[lo][4]; b4 += (bvt[hi][4] - b4) * fr;                  \
        const float* wr = wbuf + i * (JT * WS8);                              \
        _Pragma("unroll")                                                     \
        for (int jj = 0; jj < JT; ++jj) {                                     \
            const float* wp = wr + jj * WS8;                                  \
            float a = ACC[jj];                                                \
            a = fmaf(wp[0], base, a);                                         \
            a = fmaf(wp[1], b0, a);                                           \
            a = fmaf(wp[2], b1, a);                                           \
            a = fmaf(wp[3], b2, a);                                           \
            a = fmaf(wp[4], b3, a);                                           \
            a = fmaf(wp[5], b4, a);                                           \
            ACC[jj] = a;                                                      \
        }                                                                     \
    }                                                                         \
} while (0)

__global__ __launch_bounds__(NTHR) void kan_fused_kernel(
    const float* __restrict__ x,
    const float* __restrict__ cp0, const float* __restrict__ bw0,
    const float* __restrict__ sw0, const float* __restrict__ imp0,
    const float* __restrict__ cp1, const float* __restrict__ bw1,
    const float* __restrict__ sw1, const float* __restrict__ imp1,
    float* __restrict__ out)
{
    __shared__ float vbuf[64][NTHR + 1];
    __shared__ float wbuf[64 * JT * WS8];
    __shared__ float bvt[3][8];

    const int tid = threadIdx.x;

    if (tid < 3) {
        float gv = -1.0f + (float)tid;
        float e[5];
        float s = 0.0f;
        #pragma unroll
        for (int i = 0; i < 5; ++i) {
            float c = -0.8125f + 0.325f * (float)i;
            float d = (gv - c) * (1.0f / 0.65f);
            e[i] = expf(-d * d);
            s += e[i];
        }
        float inv = 1.0f / (s + 1e-6f);
        #pragma unroll
        for (int i = 0; i < 5; ++i) bvt[tid][i] = e[i] * inv;
    }

    {
        const float4* xg = (const float4*)(x + (size_t)blockIdx.x * (NTHR * 64));
        #pragma unroll
        for (int it = 0; it < 16; ++it) {
            int e4 = tid + it * NTHR;
            float4 v = xg[e4];
            int r  = e4 >> 4;
            int ib = (e4 & 15) << 2;
            vbuf[ib + 0][r] = v.x;
            vbuf[ib + 1][r] = v.y;
            vbuf[ib + 2][r] = v.z;
            vbuf[ib + 3][r] = v.w;
        }
    }
    __syncthreads();

    float h0[32] = {}, h1[32] = {}, h2[32] = {}, h3[32] = {};
    STAGE_L0(0);   __syncthreads(); COMPUTE_TILE(h0); __syncthreads();
    STAGE_L0(32);  __syncthreads(); COMPUTE_TILE(h1); __syncthreads();
    STAGE_L0(64);  __syncthreads(); COMPUTE_TILE(h2); __syncthreads();
    STAGE_L0(96);  __syncthreads(); COMPUTE_TILE(h3); __syncthreads();

    #pragma unroll
    for (int i = 0; i < 32; ++i) vbuf[i][tid] = h0[i];
    #pragma unroll
    for (int i = 0; i < 32; ++i) vbuf[32 + i][tid] = h1[i];

    float o0[32] = {}, o1[32] = {};
    STAGE_L1(0, 0);   __syncthreads(); COMPUTE_TILE(o0); __syncthreads();
    STAGE_L1(0, 32);  __syncthreads(); COMPUTE_TILE(o1); __syncthreads();

    #pragma unroll
    for (int i = 0; i < 32; ++i) vbuf[i][tid] = h2[i];
    #pragma unroll
    for (int i = 0; i < 32; ++i) vbuf[32 + i][tid] = h3[i];

    STAGE_L1(64, 0);  __syncthreads(); COMPUTE_TILE(o0); __syncthreads();
    STAGE_L1(64, 32); __syncthreads(); COMPUTE_TILE(o1);

    float4* og = (float4*)(out + (size_t)blockIdx.x * (NTHR * 64) + (size_t)tid * 64);
    #pragma unroll
    for (int q = 0; q < 8; ++q)
        og[q] = make_float4(o0[4 * q + 0], o0[4 * q + 1], o0[4 * q + 2], o0[4 * q + 3]);
    #pragma unroll
    for (int q = 0; q < 8; ++q)
        og[8 + q] = make_float4(o1[4 * q + 0], o1[4 * q + 1], o1[4 * q + 2], o1[4 * q + 3]);
}

// =================================== launch ===================================
extern "C" void kernel_launch(void* const* d_in, const int* in_sizes, int n_in,
                              void* d_out, int out_size, void* d_ws, size_t ws_size,
                              hipStream_t stream) {
    const float* x    = (const float*)d_in[0];
    const float* cp0  = (const float*)d_in[1];
    const float* bw0  = (const float*)d_in[2];
    const float* sw0  = (const float*)d_in[3];
    const float* imp0 = (const float*)d_in[4];
    const float* cp1  = (const float*)d_in[5];
    const float* bw1  = (const float*)d_in[6];
    const float* sw1  = (const float*)d_in[7];
    const float* imp1 = (const float*)d_in[8];
    float* out = (float*)d_out;

    const int B = in_sizes[0] / 64;                 // 131072
    const size_t need = 98304 * sizeof(_Float16);   // 192 KB combined weights

    if (ws_size >= need && (B % BM) == 0) {
        _Float16* W0t = (_Float16*)d_ws;
        _Float16* W1t = W0t + 49152;
        kan_combine_w<<<384, 256, 0, stream>>>(cp0, bw0, sw0, imp0,
                                               cp1, bw1, sw1, imp1, W0t, W1t);
        kan_mfma_kernel<<<B / BM, TPB, 0, stream>>>(x, W0t, W1t, out);
    } else {
        kan_fused_kernel<<<B / NTHR, NTHR, 0, stream>>>(
            x, cp0, bw0, sw0, imp0, cp1, bw1, sw1, imp1, out);
    }
}